// Round 1
// baseline (4543.709 us; speedup 1.0000x reference)
//
#include <hip/hip_runtime.h>

#define TT   8192
#define DDIM 2048
#define HDIM 7168
#define NEXP 8

typedef __attribute__((ext_vector_type(8))) short bf16x8;
typedef __attribute__((ext_vector_type(4))) short short4v;
typedef __attribute__((ext_vector_type(4))) float f32x4;

__device__ __forceinline__ unsigned short f2bf(float f) {
  unsigned int u = __builtin_bit_cast(unsigned int, f);
  u += 0x7fffu + ((u >> 16) & 1u);   // RNE
  return (unsigned short)(u >> 16);
}

__device__ __forceinline__ void gload_lds16(const void* gp, void* lp) {
  __builtin_amdgcn_global_load_lds((__attribute__((address_space(1))) void*)gp,
                                   (__attribute__((address_space(3))) void*)lp,
                                   16, 0, 0);
}

__device__ __forceinline__ void mfma16(f32x4& c, bf16x8 a, bf16x8 b) {
  asm("v_mfma_f32_16x16x32_bf16 %0, %1, %2, %0" : "+v"(c) : "v"(a), "v"(b));
}

// ---------------- x fp32 -> bf16 ----------------
__global__ __launch_bounds__(256) void cvt_x_kernel(const float* __restrict__ x,
                                                    unsigned short* __restrict__ xbf) {
  size_t i = ((size_t)blockIdx.x * 256 + threadIdx.x) * 4;
  if (i >= (size_t)TT * DDIM) return;
  float4 v = *(const float4*)(x + i);
  short4v s;
  s[0] = (short)f2bf(v.x); s[1] = (short)f2bf(v.y);
  s[2] = (short)f2bf(v.z); s[3] = (short)f2bf(v.w);
  *(short4v*)(xbf + i) = s;
}

// ---------------- gate: logits + top2 + softmax + counts ----------------
__global__ __launch_bounds__(256) void gate_kernel(const float* __restrict__ x,
                                                   const float* __restrict__ gw,
                                                   int* __restrict__ route_e,
                                                   float* __restrict__ route_w,
                                                   int* __restrict__ counts) {
  int t = blockIdx.x;
  int tid = threadIdx.x;
  const float* xr = x + (size_t)t * DDIM;
  float p[NEXP];
#pragma unroll
  for (int e = 0; e < NEXP; ++e) p[e] = 0.f;
#pragma unroll
  for (int c = 0; c < DDIM / (256 * 4); ++c) {
    int d = (c * 256 + tid) * 4;
    float4 xv = *(const float4*)(xr + d);
#pragma unroll
    for (int e = 0; e < NEXP; ++e) {
      float4 wv = *(const float4*)(gw + (size_t)e * DDIM + d);
      p[e] += xv.x * wv.x + xv.y * wv.y + xv.z * wv.z + xv.w * wv.w;
    }
  }
  __shared__ float red[NEXP][4];
  int lane = tid & 63, wid = tid >> 6;
#pragma unroll
  for (int e = 0; e < NEXP; ++e) {
    float v = p[e];
    for (int o = 32; o > 0; o >>= 1) v += __shfl_down(v, o);
    if (lane == 0) red[e][wid] = v;
  }
  __syncthreads();
  if (tid == 0) {
    float lg[NEXP];
#pragma unroll
    for (int e = 0; e < NEXP; ++e) lg[e] = red[e][0] + red[e][1] + red[e][2] + red[e][3];
    int i0 = 0;
#pragma unroll
    for (int e = 1; e < NEXP; ++e) if (lg[e] > lg[i0]) i0 = e;
    int i1 = -1;
#pragma unroll
    for (int e = 0; e < NEXP; ++e) {
      if (e == i0) continue;
      if (i1 < 0 || lg[e] > lg[i1]) i1 = e;
    }
    float w0 = 1.f / (1.f + __expf(lg[i1] - lg[i0]));
    float w1 = 1.f - w0;
    route_e[t * 2 + 0] = i0;  route_e[t * 2 + 1] = i1;
    route_w[t * 2 + 0] = w0;  route_w[t * 2 + 1] = w1;
    atomicAdd(&counts[i0], 1);
    atomicAdd(&counts[i1], 1);
  }
}

__global__ void scan_kernel(const int* __restrict__ counts, int* __restrict__ offsets,
                            int* __restrict__ cursor) {
  if (threadIdx.x == 0 && blockIdx.x == 0) {
    int o = 0;
    for (int e = 0; e < NEXP; ++e) { offsets[e] = o; cursor[e] = o; o += counts[e]; }
  }
}

__global__ __launch_bounds__(256) void scatter_kernel(const int* __restrict__ route_e,
                                                      const float* __restrict__ route_w,
                                                      int* __restrict__ cursor,
                                                      int* __restrict__ tok_list,
                                                      float* __restrict__ tok_w) {
  int t = blockIdx.x * 256 + threadIdx.x;
  if (t >= TT) return;
#pragma unroll
  for (int s = 0; s < 2; ++s) {
    int e = route_e[t * 2 + s];
    int p = atomicAdd(&cursor[e], 1);
    tok_list[p] = t;
    tok_w[p] = route_w[t * 2 + s];
  }
}

// ---------------- w2 [H,D] fp32 -> w2t [D,H] bf16 ----------------
__global__ __launch_bounds__(256) void transpose_w2_kernel(const float* __restrict__ w2,
                                                           unsigned short* __restrict__ w2t,
                                                           int expert_fixed) {
  int e = expert_fixed >= 0 ? expert_fixed : (int)blockIdx.z;
  const float* src = w2 + (size_t)e * HDIM * DDIM;
  unsigned short* dst = w2t + (expert_fixed >= 0 ? (size_t)0 : (size_t)e * DDIM * HDIM);
  int h0 = blockIdx.x * 64, d0 = blockIdx.y * 64;
  __shared__ __align__(8) unsigned short tile[64 * 66];   // stride 66 elems: conflict-light
  int tid = threadIdx.x;
  int hr = tid >> 2;
#pragma unroll
  for (int j = 0; j < 4; ++j) {
    int f4 = (tid & 3) + j * 4;
    float4 v = *(const float4*)(src + (size_t)(h0 + hr) * DDIM + d0 + f4 * 4);
    unsigned int lo = (unsigned int)f2bf(v.x) | ((unsigned int)f2bf(v.y) << 16);
    unsigned int hi = (unsigned int)f2bf(v.z) | ((unsigned int)f2bf(v.w) << 16);
    char* bp = (char*)tile + hr * 132 + f4 * 8;
    *(unsigned int*)bp = lo;
    *(unsigned int*)(bp + 4) = hi;
  }
  __syncthreads();
  int dr = tid >> 2;
  int hbase = (tid & 3) * 16;
  unsigned short vals[16];
#pragma unroll
  for (int i = 0; i < 16; ++i)
    vals[i] = *(unsigned short*)((char*)tile + (hbase + i) * 132 + dr * 2);
  unsigned short* op = dst + (size_t)(d0 + dr) * HDIM + h0 + hbase;
#pragma unroll
  for (int j = 0; j < 4; ++j) {
    short4v s;
    s[0] = (short)vals[j * 4 + 0]; s[1] = (short)vals[j * 4 + 1];
    s[2] = (short)vals[j * 4 + 2]; s[3] = (short)vals[j * 4 + 3];
    *(short4v*)(op + j * 4) = s;
  }
}

// ---------------- GEMM1: g = silu(Xe w1^T) * (Xe w3^T), dual-output fused ----------------
__global__ __launch_bounds__(256, 2) void gemm1_kernel(
    const unsigned short* __restrict__ xbf, const float* __restrict__ w1,
    const float* __restrict__ w3, const int* __restrict__ tok_list,
    const int* __restrict__ counts, const int* __restrict__ offsets,
    unsigned short* __restrict__ g, int expert_fixed, int r0) {
  int e = expert_fixed >= 0 ? expert_fixed : (int)blockIdx.z;
  int cnt = counts[e];
  int mbase = r0 + (int)blockIdx.x * 128;
  if (mbase >= cnt) return;
  int off = offsets[e];
  int gshift = expert_fixed >= 0 ? -r0 : off;
  int nbase = (int)blockIdx.y * 128;
  int rows = cnt - mbase; if (rows > 128) rows = 128;

  const float* w1e = w1 + (size_t)e * HDIM * DDIM;
  const float* w3e = w3 + (size_t)e * HDIM * DDIM;

  __shared__ __align__(16) unsigned short As[128 * 32];
  __shared__ __align__(16) unsigned short B1s[128 * 32];
  __shared__ __align__(16) unsigned short B3s[128 * 32];

  int tid = threadIdx.x, lane = tid & 63, wid = tid >> 6;
  int wr = wid >> 1, wc = wid & 1;

  // A staging: wave wid stages rows wid*32 + t*16 + (lane>>2), 16B chunk (lane&3)
  size_t tokoff[2];
#pragma unroll
  for (int t2 = 0; t2 < 2; ++t2) {
    int r = wid * 32 + t2 * 16 + (lane >> 2);
    int m = mbase + r; if (m > cnt - 1) m = cnt - 1;
    int tok = tok_list[off + m];
    tokoff[t2] = (size_t)tok * (DDIM * 2) + (size_t)((lane & 3) * 16);
  }
  // B staging: thread covers (n = c>>3, f4 = c&7), c = tid + i*256
  const float* bp1[4]; const float* bp3[4]; int bidx[4];
#pragma unroll
  for (int i = 0; i < 4; ++i) {
    int c = tid + i * 256;
    int n = c >> 3, f4 = c & 7;
    bidx[i] = n * 32 + f4 * 4;
    bp1[i] = w1e + (size_t)(nbase + n) * DDIM + f4 * 4;
    bp3[i] = w3e + (size_t)(nbase + n) * DDIM + f4 * 4;
  }

  f32x4 zv = {0.f, 0.f, 0.f, 0.f};
  f32x4 acc1[4][4], acc3[4][4];
#pragma unroll
  for (int mi = 0; mi < 4; ++mi)
#pragma unroll
    for (int ni = 0; ni < 4; ++ni) { acc1[mi][ni] = zv; acc3[mi][ni] = zv; }

  const char* xb = (const char*)xbf;
  char* AsB = (char*)As + wid * 2048;

  for (int ks = 0; ks < DDIM / 32; ++ks) {
    __syncthreads();
    gload_lds16(xb + tokoff[0] + (size_t)ks * 64, AsB);
    gload_lds16(xb + tokoff[1] + (size_t)ks * 64, AsB + 1024);
#pragma unroll
    for (int i = 0; i < 4; ++i) {
      float4 v1 = *(const float4*)(bp1[i] + ks * 32);
      float4 v3 = *(const float4*)(bp3[i] + ks * 32);
      short4v s1, s3;
      s1[0] = (short)f2bf(v1.x); s1[1] = (short)f2bf(v1.y);
      s1[2] = (short)f2bf(v1.z); s1[3] = (short)f2bf(v1.w);
      s3[0] = (short)f2bf(v3.x); s3[1] = (short)f2bf(v3.y);
      s3[2] = (short)f2bf(v3.z); s3[3] = (short)f2bf(v3.w);
      *(short4v*)&B1s[bidx[i]] = s1;
      *(short4v*)&B3s[bidx[i]] = s3;
    }
    __syncthreads();
    bf16x8 a[4];
#pragma unroll
    for (int mi = 0; mi < 4; ++mi)
      a[mi] = *(const bf16x8*)&As[(wr * 64 + mi * 16 + (lane & 15)) * 32 + (lane >> 4) * 8];
#pragma unroll
    for (int ni = 0; ni < 4; ++ni) {
      int nrow = (wc * 64 + ni * 16 + (lane & 15)) * 32 + (lane >> 4) * 8;
      bf16x8 b1 = *(const bf16x8*)&B1s[nrow];
      bf16x8 b3 = *(const bf16x8*)&B3s[nrow];
#pragma unroll
      for (int mi = 0; mi < 4; ++mi) {
        mfma16(acc1[mi][ni], a[mi], b1);
        mfma16(acc3[mi][ni], a[mi], b3);
      }
    }
  }
  // epilogue: silu(h1)*h3 -> g (bf16)
#pragma unroll
  for (int mi = 0; mi < 4; ++mi) {
#pragma unroll
    for (int q = 0; q < 4; ++q) {
      int rl = wr * 64 + mi * 16 + (lane >> 4) * 4 + q;
      if (rl >= rows) continue;
      size_t grow = (size_t)(mbase + rl + gshift);
      unsigned short* gp = g + grow * HDIM + nbase + wc * 64 + (lane & 15);
#pragma unroll
      for (int ni = 0; ni < 4; ++ni) {
        float v1 = acc1[mi][ni][q];
        float v3 = acc3[mi][ni][q];
        float gv = (v1 / (1.f + __expf(-v1))) * v3;
        gp[ni * 16] = f2bf(gv);
      }
    }
  }
}

// ---------------- GEMM2: out += we * (g @ w2) via w2t, atomic epilogue ----------------
__global__ __launch_bounds__(256, 2) void gemm2_kernel(
    const unsigned short* __restrict__ g, const unsigned short* __restrict__ w2t,
    const int* __restrict__ tok_list, const float* __restrict__ tok_w,
    const int* __restrict__ counts, const int* __restrict__ offsets,
    float* __restrict__ out, int expert_fixed, int r0) {
  int e = expert_fixed >= 0 ? expert_fixed : (int)blockIdx.z;
  int cnt = counts[e];
  int mbase = r0 + (int)blockIdx.x * 128;
  if (mbase >= cnt) return;
  int off = offsets[e];
  int gshift = expert_fixed >= 0 ? -r0 : off;
  int nbase = (int)blockIdx.y * 128;
  int rows = cnt - mbase; if (rows > 128) rows = 128;
  const unsigned short* w2te = w2t + (expert_fixed >= 0 ? (size_t)0 : (size_t)e * DDIM * HDIM);

  __shared__ __align__(16) unsigned short As[128 * 32];
  __shared__ __align__(16) unsigned short Bs[128 * 32];

  int tid = threadIdx.x, lane = tid & 63, wid = tid >> 6;
  int wr = wid >> 1, wc = wid & 1;

  size_t aoff[2], boff[2];
#pragma unroll
  for (int t2 = 0; t2 < 2; ++t2) {
    int r = wid * 32 + t2 * 16 + (lane >> 2);
    int m = mbase + r; if (m > cnt - 1) m = cnt - 1;
    aoff[t2] = (size_t)(m + gshift) * (HDIM * 2) + (size_t)((lane & 3) * 16);
    boff[t2] = (size_t)(nbase + r) * (HDIM * 2) + (size_t)((lane & 3) * 16);
  }

  f32x4 zv = {0.f, 0.f, 0.f, 0.f};
  f32x4 acc[4][4];
#pragma unroll
  for (int mi = 0; mi < 4; ++mi)
#pragma unroll
    for (int ni = 0; ni < 4; ++ni) acc[mi][ni] = zv;

  const char* gb = (const char*)g;
  const char* wb = (const char*)w2te;
  char* AsB = (char*)As + wid * 2048;
  char* BsB = (char*)Bs + wid * 2048;

  for (int ks = 0; ks < HDIM / 32; ++ks) {
    __syncthreads();
    gload_lds16(gb + aoff[0] + (size_t)ks * 64, AsB);
    gload_lds16(gb + aoff[1] + (size_t)ks * 64, AsB + 1024);
    gload_lds16(wb + boff[0] + (size_t)ks * 64, BsB);
    gload_lds16(wb + boff[1] + (size_t)ks * 64, BsB + 1024);
    __syncthreads();
    bf16x8 a[4];
#pragma unroll
    for (int mi = 0; mi < 4; ++mi)
      a[mi] = *(const bf16x8*)&As[(wr * 64 + mi * 16 + (lane & 15)) * 32 + (lane >> 4) * 8];
#pragma unroll
    for (int ni = 0; ni < 4; ++ni) {
      bf16x8 b = *(const bf16x8*)&Bs[(wc * 64 + ni * 16 + (lane & 15)) * 32 + (lane >> 4) * 8];
#pragma unroll
      for (int mi = 0; mi < 4; ++mi) mfma16(acc[mi][ni], a[mi], b);
    }
  }
#pragma unroll
  for (int mi = 0; mi < 4; ++mi) {
#pragma unroll
    for (int q = 0; q < 4; ++q) {
      int rl = wr * 64 + mi * 16 + (lane >> 4) * 4 + q;
      if (rl >= rows) continue;
      int m = mbase + rl;
      int tok = tok_list[off + m];
      float wt = tok_w[off + m];
      float* op = out + (size_t)tok * DDIM + nbase + wc * 64 + (lane & 15);
#pragma unroll
      for (int ni = 0; ni < 4; ++ni)
        atomicAdd(op + ni * 16, acc[mi][ni][q] * wt);
    }
  }
}

extern "C" void kernel_launch(void* const* d_in, const int* in_sizes, int n_in,
                              void* d_out, int out_size, void* d_ws, size_t ws_size,
                              hipStream_t stream) {
  const float* x      = (const float*)d_in[0];
  const float* gate_w = (const float*)d_in[1];
  const float* w1     = (const float*)d_in[2];
  const float* w2     = (const float*)d_in[3];
  const float* w3     = (const float*)d_in[4];
  float* out = (float*)d_out;
  char* ws = (char*)d_ws;

  size_t o = 0;
  int* counts  = (int*)(ws + o);
  int* offsets = counts + 8;
  int* cursor  = counts + 16;
  o += 256;
  int*   route_e = (int*)(ws + o);   o += (size_t)TT * 2 * 4;
  float* route_w = (float*)(ws + o); o += (size_t)TT * 2 * 4;
  int*   tok_list = (int*)(ws + o);  o += (size_t)TT * 2 * 4;
  float* tok_w = (float*)(ws + o);   o += (size_t)TT * 2 * 4;
  unsigned short* xbf = (unsigned short*)(ws + o); o += (size_t)TT * DDIM * 2;
  size_t fixed = o;
  size_t gfull   = (size_t)TT * 2 * HDIM * 2;       // 16384 packed rows
  size_t w2tfull = (size_t)NEXP * DDIM * HDIM * 2;

  hipMemsetAsync(counts, 0, 8 * sizeof(int), stream);
  hipMemsetAsync(out, 0, (size_t)TT * DDIM * sizeof(float), stream);
  cvt_x_kernel<<<(TT * DDIM / 4 + 255) / 256, 256, 0, stream>>>(x, xbf);
  gate_kernel<<<TT, 256, 0, stream>>>(x, gate_w, route_e, route_w, counts);
  scan_kernel<<<1, 64, 0, stream>>>(counts, offsets, cursor);
  scatter_kernel<<<(TT + 255) / 256, 256, 0, stream>>>(route_e, route_w, cursor, tok_list, tok_w);

  if (ws_size >= fixed + gfull + w2tfull) {
    // Path A: all experts in parallel (blockIdx.z = expert), packed g rows
    unsigned short* gbuf = (unsigned short*)(ws + fixed);
    unsigned short* w2t  = (unsigned short*)(ws + fixed + gfull);
    transpose_w2_kernel<<<dim3(HDIM / 64, DDIM / 64, NEXP), 256, 0, stream>>>(w2, w2t, -1);
    gemm1_kernel<<<dim3(TT / 128, HDIM / 128, NEXP), 256, 0, stream>>>(
        xbf, w1, w3, tok_list, counts, offsets, gbuf, -1, 0);
    gemm2_kernel<<<dim3(TT / 128, DDIM / 128, NEXP), 256, 0, stream>>>(
        gbuf, w2t, tok_list, tok_w, counts, offsets, out, -1, 0);
  } else {
    // Path B: sequential per-expert, row-chunked to fit ws
    size_t w2tchunk = (size_t)DDIM * HDIM * 2;
    unsigned short* w2t  = (unsigned short*)(ws + fixed);
    unsigned short* gbuf = (unsigned short*)(ws + fixed + w2tchunk);
    size_t avail = ws_size > fixed + w2tchunk ? ws_size - fixed - w2tchunk : 0;
    long ch = (long)(avail / ((size_t)HDIM * 2));
    ch = (ch / 128) * 128;
    if (ch < 128) ch = 128;
    if (ch > TT) ch = TT;
    int nc = (int)((TT + ch - 1) / ch);
    for (int e = 0; e < NEXP; ++e) {
      transpose_w2_kernel<<<dim3(HDIM / 64, DDIM / 64, 1), 256, 0, stream>>>(w2, w2t, e);
      for (int c = 0; c < nc; ++c) {
        gemm1_kernel<<<dim3((int)ch / 128, HDIM / 128, 1), 256, 0, stream>>>(
            xbf, w1, w3, tok_list, counts, offsets, gbuf, e, c * (int)ch);
        gemm2_kernel<<<dim3((int)ch / 128, DDIM / 128, 1), 256, 0, stream>>>(
            gbuf, w2t, tok_list, tok_w, counts, offsets, out, e, c * (int)ch);
      }
    }
  }
}

// Round 2
// 2692.783 us; speedup vs baseline: 1.6874x; 1.6874x over previous
//
#include <hip/hip_runtime.h>

#define TT   8192
#define DDIM 2048
#define HDIM 7168
#define NEXP 8
#define NY1  (HDIM / 128)   // 56
#define NY2  (DDIM / 128)   // 16
#define NXB  (TT / 128)     // 64

typedef __attribute__((ext_vector_type(8))) short bf16x8;
typedef __attribute__((ext_vector_type(4))) short short4v;
typedef __attribute__((ext_vector_type(4))) float f32x4;

__device__ __forceinline__ unsigned short f2bf(float f) {
  unsigned int u = __builtin_bit_cast(unsigned int, f);
  u += 0x7fffu + ((u >> 16) & 1u);   // RNE
  return (unsigned short)(u >> 16);
}

__device__ __forceinline__ void gload_lds16(const void* gp, void* lp) {
  __builtin_amdgcn_global_load_lds((__attribute__((address_space(1))) void*)gp,
                                   (__attribute__((address_space(3))) void*)lp,
                                   16, 0, 0);
}

__device__ __forceinline__ void mfma16(f32x4& c, bf16x8 a, bf16x8 b) {
  asm("v_mfma_f32_16x16x32_bf16 %0, %1, %2, %0" : "+v"(c) : "v"(a), "v"(b));
}

// ---------------- fp32 -> bf16 elementwise (grid-stride, float4-wide) ----------------
__global__ __launch_bounds__(256) void cvt_bf16_kernel(const float* __restrict__ src,
                                                       unsigned short* __restrict__ dst,
                                                       long n4) {
  long i = (long)blockIdx.x * 256 + threadIdx.x;
  long stride = (long)gridDim.x * 256;
  for (; i < n4; i += stride) {
    float4 v = ((const float4*)src)[i];
    short4v s;
    s[0] = (short)f2bf(v.x); s[1] = (short)f2bf(v.y);
    s[2] = (short)f2bf(v.z); s[3] = (short)f2bf(v.w);
    ((short4v*)dst)[i] = s;
  }
}

// ---------------- gate: logits + top2 + softmax + counts ----------------
__global__ __launch_bounds__(256) void gate_kernel(const float* __restrict__ x,
                                                   const float* __restrict__ gw,
                                                   int* __restrict__ route_e,
                                                   float* __restrict__ route_w,
                                                   int* __restrict__ counts) {
  int t = blockIdx.x;
  int tid = threadIdx.x;
  const float* xr = x + (size_t)t * DDIM;
  float p[NEXP];
#pragma unroll
  for (int e = 0; e < NEXP; ++e) p[e] = 0.f;
#pragma unroll
  for (int c = 0; c < DDIM / (256 * 4); ++c) {
    int d = (c * 256 + tid) * 4;
    float4 xv = *(const float4*)(xr + d);
#pragma unroll
    for (int e = 0; e < NEXP; ++e) {
      float4 wv = *(const float4*)(gw + (size_t)e * DDIM + d);
      p[e] += xv.x * wv.x + xv.y * wv.y + xv.z * wv.z + xv.w * wv.w;
    }
  }
  __shared__ float red[NEXP][4];
  int lane = tid & 63, wid = tid >> 6;
#pragma unroll
  for (int e = 0; e < NEXP; ++e) {
    float v = p[e];
    for (int o = 32; o > 0; o >>= 1) v += __shfl_down(v, o);
    if (lane == 0) red[e][wid] = v;
  }
  __syncthreads();
  if (tid == 0) {
    float lg[NEXP];
#pragma unroll
    for (int e = 0; e < NEXP; ++e) lg[e] = red[e][0] + red[e][1] + red[e][2] + red[e][3];
    int i0 = 0;
#pragma unroll
    for (int e = 1; e < NEXP; ++e) if (lg[e] > lg[i0]) i0 = e;
    int i1 = -1;
#pragma unroll
    for (int e = 0; e < NEXP; ++e) {
      if (e == i0) continue;
      if (i1 < 0 || lg[e] > lg[i1]) i1 = e;
    }
    float w0 = 1.f / (1.f + __expf(lg[i1] - lg[i0]));
    float w1 = 1.f - w0;
    route_e[t * 2 + 0] = i0;  route_e[t * 2 + 1] = i1;
    route_w[t * 2 + 0] = w0;  route_w[t * 2 + 1] = w1;
    atomicAdd(&counts[i0], 1);
    atomicAdd(&counts[i1], 1);
  }
}

__global__ void scan_kernel(const int* __restrict__ counts, int* __restrict__ offsets,
                            int* __restrict__ cursor) {
  if (threadIdx.x == 0 && blockIdx.x == 0) {
    int o = 0;
    for (int e = 0; e < NEXP; ++e) { offsets[e] = o; cursor[e] = o; o += counts[e]; }
  }
}

__global__ __launch_bounds__(256) void scatter_kernel(const int* __restrict__ route_e,
                                                      const float* __restrict__ route_w,
                                                      int* __restrict__ cursor,
                                                      int* __restrict__ tok_list,
                                                      float* __restrict__ tok_w) {
  int t = blockIdx.x * 256 + threadIdx.x;
  if (t >= TT) return;
#pragma unroll
  for (int s = 0; s < 2; ++s) {
    int e = route_e[t * 2 + s];
    int p = atomicAdd(&cursor[e], 1);
    tok_list[p] = t;
    tok_w[p] = route_w[t * 2 + s];
  }
}

// ---------------- w2 [H,D] fp32 -> w2t [D,H] bf16 ----------------
__global__ __launch_bounds__(256) void transpose_w2_kernel(const float* __restrict__ w2,
                                                           unsigned short* __restrict__ w2t,
                                                           int expert_fixed) {
  int e = expert_fixed >= 0 ? expert_fixed : (int)blockIdx.z;
  const float* src = w2 + (size_t)e * HDIM * DDIM;
  unsigned short* dst = w2t + (expert_fixed >= 0 ? (size_t)0 : (size_t)e * DDIM * HDIM);
  int h0 = blockIdx.x * 64, d0 = blockIdx.y * 64;
  __shared__ __align__(8) unsigned short tile[64 * 66];
  int tid = threadIdx.x;
  int hr = tid >> 2;
#pragma unroll
  for (int j = 0; j < 4; ++j) {
    int f4 = (tid & 3) + j * 4;
    float4 v = *(const float4*)(src + (size_t)(h0 + hr) * DDIM + d0 + f4 * 4);
    unsigned int lo = (unsigned int)f2bf(v.x) | ((unsigned int)f2bf(v.y) << 16);
    unsigned int hi = (unsigned int)f2bf(v.z) | ((unsigned int)f2bf(v.w) << 16);
    char* bp = (char*)tile + hr * 132 + f4 * 8;
    *(unsigned int*)bp = lo;
    *(unsigned int*)(bp + 4) = hi;
  }
  __syncthreads();
  int dr = tid >> 2;
  int hbase = (tid & 3) * 16;
  unsigned short vals[16];
#pragma unroll
  for (int i = 0; i < 16; ++i)
    vals[i] = *(unsigned short*)((char*)tile + (hbase + i) * 132 + dr * 2);
  unsigned short* op = dst + (size_t)(d0 + dr) * HDIM + h0 + hbase;
#pragma unroll
  for (int j = 0; j < 4; ++j) {
    short4v s;
    s[0] = (short)vals[j * 4 + 0]; s[1] = (short)vals[j * 4 + 1];
    s[2] = (short)vals[j * 4 + 2]; s[3] = (short)vals[j * 4 + 3];
    *(short4v*)(op + j * 4) = s;
  }
}

// ---------------- GEMM1: g = silu(Xe w1^T) * (Xe w3^T), 2-phase dbuf, all-bf16 ----------------
__global__ __launch_bounds__(256, 2) void gemm1_kernel(
    const unsigned short* __restrict__ xbf, const unsigned short* __restrict__ w1b,
    const unsigned short* __restrict__ w3b, const int* __restrict__ tok_list,
    const int* __restrict__ counts, const int* __restrict__ offsets,
    unsigned short* __restrict__ g, int expert_fixed) {
  // flat grid, bijective XCD swizzle (nwg % 8 == 0)
  int nwg = gridDim.x;
  int orig = blockIdx.x;
  int wg = (orig & 7) * (nwg >> 3) + (orig >> 3);
  int nx = wg % NXB;
  int rem = wg / NXB;
  int ny = rem % NY1;
  int e = expert_fixed >= 0 ? expert_fixed : rem / NY1;

  int cnt = counts[e];
  int mbase = nx * 128;
  if (mbase >= cnt) return;
  int off = offsets[e];
  int gshift = expert_fixed >= 0 ? 0 : off;
  int nbase = ny * 128;
  int rows = cnt - mbase; if (rows > 128) rows = 128;

  const unsigned short* w1e = expert_fixed >= 0 ? w1b : w1b + (size_t)e * HDIM * DDIM;
  const unsigned short* w3e = expert_fixed >= 0 ? w3b : w3b + (size_t)e * HDIM * DDIM;

  __shared__ __align__(16) unsigned short As[2][128 * 32];
  __shared__ __align__(16) unsigned short B1s[2][128 * 32];
  __shared__ __align__(16) unsigned short B3s[2][128 * 32];

  int tid = threadIdx.x, lane = tid & 63, wid = tid >> 6;
  int wr = wid >> 1, wc = wid & 1;

  // staging addresses: wave wid stages rows wid*32 + t2*16 + (lane>>2), chunk (lane&3)*16B
  size_t tokoff[2];
  const char* w1p[2]; const char* w3p[2];
#pragma unroll
  for (int t2 = 0; t2 < 2; ++t2) {
    int r = wid * 32 + t2 * 16 + (lane >> 2);
    int m = mbase + r; if (m > cnt - 1) m = cnt - 1;
    int tok = tok_list[off + m];
    tokoff[t2] = (size_t)tok * (DDIM * 2) + (size_t)((lane & 3) * 16);
    int br = nbase + r;
    w1p[t2] = (const char*)w1e + (size_t)br * (DDIM * 2) + (lane & 3) * 16;
    w3p[t2] = (const char*)w3e + (size_t)br * (DDIM * 2) + (lane & 3) * 16;
  }
  const char* xb = (const char*)xbf;

  f32x4 zv = {0.f, 0.f, 0.f, 0.f};
  f32x4 acc1[4][4], acc3[4][4];
#pragma unroll
  for (int mi = 0; mi < 4; ++mi)
#pragma unroll
    for (int ni = 0; ni < 4; ++ni) { acc1[mi][ni] = zv; acc3[mi][ni] = zv; }

  auto stage = [&](int buf, int ks) {
    char* Ad  = (char*)&As[buf][0]  + wid * 2048;
    char* B1d = (char*)&B1s[buf][0] + wid * 2048;
    char* B3d = (char*)&B3s[buf][0] + wid * 2048;
    size_t ko = (size_t)ks * 64;
    gload_lds16(xb + tokoff[0] + ko, Ad);
    gload_lds16(xb + tokoff[1] + ko, Ad + 1024);
    gload_lds16(w1p[0] + ko, B1d);
    gload_lds16(w1p[1] + ko, B1d + 1024);
    gload_lds16(w3p[0] + ko, B3d);
    gload_lds16(w3p[1] + ko, B3d + 1024);
  };

  stage(0, 0);
  __syncthreads();
  for (int ks = 0; ks < DDIM / 32; ++ks) {
    int cur = ks & 1;
    if (ks + 1 < DDIM / 32) stage(cur ^ 1, ks + 1);
    bf16x8 a[4], b1[4], b3[4];
#pragma unroll
    for (int mi = 0; mi < 4; ++mi)
      a[mi] = *(const bf16x8*)&As[cur][(wr * 64 + mi * 16 + (lane & 15)) * 32 + (lane >> 4) * 8];
#pragma unroll
    for (int ni = 0; ni < 4; ++ni) {
      int ro = (wc * 64 + ni * 16 + (lane & 15)) * 32 + (lane >> 4) * 8;
      b1[ni] = *(const bf16x8*)&B1s[cur][ro];
      b3[ni] = *(const bf16x8*)&B3s[cur][ro];
    }
#pragma unroll
    for (int ni = 0; ni < 4; ++ni)
#pragma unroll
      for (int mi = 0; mi < 4; ++mi) {
        mfma16(acc1[mi][ni], a[mi], b1[ni]);
        mfma16(acc3[mi][ni], a[mi], b3[ni]);
      }
    __syncthreads();
  }

  // epilogue: silu(h1)*h3 -> g (bf16)
#pragma unroll
  for (int mi = 0; mi < 4; ++mi) {
#pragma unroll
    for (int q = 0; q < 4; ++q) {
      int rl = wr * 64 + mi * 16 + (lane >> 4) * 4 + q;
      if (rl >= rows) continue;
      size_t grow = (size_t)(mbase + rl + gshift);
      unsigned short* gp = g + grow * HDIM + nbase + wc * 64 + (lane & 15);
#pragma unroll
      for (int ni = 0; ni < 4; ++ni) {
        float v1 = acc1[mi][ni][q];
        float v3 = acc3[mi][ni][q];
        float gv = (v1 / (1.f + __expf(-v1))) * v3;
        gp[ni * 16] = f2bf(gv);
      }
    }
  }
}

// ---------------- GEMM2: out += we * (g @ w2) via w2t, 2-phase dbuf ----------------
__global__ __launch_bounds__(256, 2) void gemm2_kernel(
    const unsigned short* __restrict__ g, const unsigned short* __restrict__ w2t,
    const int* __restrict__ tok_list, const float* __restrict__ tok_w,
    const int* __restrict__ counts, const int* __restrict__ offsets,
    float* __restrict__ out, int expert_fixed) {
  int nwg = gridDim.x;
  int orig = blockIdx.x;
  int wg = (orig & 7) * (nwg >> 3) + (orig >> 3);
  int nx = wg % NXB;
  int rem = wg / NXB;
  int ny = rem % NY2;
  int e = expert_fixed >= 0 ? expert_fixed : rem / NY2;

  int cnt = counts[e];
  int mbase = nx * 128;
  if (mbase >= cnt) return;
  int off = offsets[e];
  int gshift = expert_fixed >= 0 ? 0 : off;
  int nbase = ny * 128;
  int rows = cnt - mbase; if (rows > 128) rows = 128;
  const unsigned short* w2te = w2t + (expert_fixed >= 0 ? (size_t)0 : (size_t)e * DDIM * HDIM);

  __shared__ __align__(16) unsigned short As[2][128 * 32];
  __shared__ __align__(16) unsigned short Bs[2][128 * 32];

  int tid = threadIdx.x, lane = tid & 63, wid = tid >> 6;
  int wr = wid >> 1, wc = wid & 1;

  size_t aoff[2], boff[2];
#pragma unroll
  for (int t2 = 0; t2 < 2; ++t2) {
    int r = wid * 32 + t2 * 16 + (lane >> 2);
    int m = mbase + r; if (m > cnt - 1) m = cnt - 1;
    aoff[t2] = (size_t)(m + gshift) * (HDIM * 2) + (size_t)((lane & 3) * 16);
    boff[t2] = (size_t)(nbase + r) * (HDIM * 2) + (size_t)((lane & 3) * 16);
  }

  f32x4 zv = {0.f, 0.f, 0.f, 0.f};
  f32x4 acc[4][4];
#pragma unroll
  for (int mi = 0; mi < 4; ++mi)
#pragma unroll
    for (int ni = 0; ni < 4; ++ni) acc[mi][ni] = zv;

  const char* gb = (const char*)g;
  const char* wb = (const char*)w2te;

  auto stage = [&](int buf, int ks) {
    char* Ad = (char*)&As[buf][0] + wid * 2048;
    char* Bd = (char*)&Bs[buf][0] + wid * 2048;
    size_t ko = (size_t)ks * 64;
    gload_lds16(gb + aoff[0] + ko, Ad);
    gload_lds16(gb + aoff[1] + ko, Ad + 1024);
    gload_lds16(wb + boff[0] + ko, Bd);
    gload_lds16(wb + boff[1] + ko, Bd + 1024);
  };

  stage(0, 0);
  __syncthreads();
  for (int ks = 0; ks < HDIM / 32; ++ks) {
    int cur = ks & 1;
    if (ks + 1 < HDIM / 32) stage(cur ^ 1, ks + 1);
    bf16x8 a[4], b[4];
#pragma unroll
    for (int mi = 0; mi < 4; ++mi)
      a[mi] = *(const bf16x8*)&As[cur][(wr * 64 + mi * 16 + (lane & 15)) * 32 + (lane >> 4) * 8];
#pragma unroll
    for (int ni = 0; ni < 4; ++ni)
      b[ni] = *(const bf16x8*)&Bs[cur][(wc * 64 + ni * 16 + (lane & 15)) * 32 + (lane >> 4) * 8];
#pragma unroll
    for (int ni = 0; ni < 4; ++ni)
#pragma unroll
      for (int mi = 0; mi < 4; ++mi) mfma16(acc[mi][ni], a[mi], b[ni]);
    __syncthreads();
  }
#pragma unroll
  for (int mi = 0; mi < 4; ++mi) {
#pragma unroll
    for (int q = 0; q < 4; ++q) {
      int rl = wr * 64 + mi * 16 + (lane >> 4) * 4 + q;
      if (rl >= rows) continue;
      int m = mbase + rl;
      int tok = tok_list[off + m];
      float wt = tok_w[off + m];
      float* op = out + (size_t)tok * DDIM + nbase + wc * 64 + (lane & 15);
#pragma unroll
      for (int ni = 0; ni < 4; ++ni)
        atomicAdd(op + ni * 16, acc[mi][ni][q] * wt);
    }
  }
}

extern "C" void kernel_launch(void* const* d_in, const int* in_sizes, int n_in,
                              void* d_out, int out_size, void* d_ws, size_t ws_size,
                              hipStream_t stream) {
  const float* x      = (const float*)d_in[0];
  const float* gate_w = (const float*)d_in[1];
  const float* w1     = (const float*)d_in[2];
  const float* w2     = (const float*)d_in[3];
  const float* w3     = (const float*)d_in[4];
  float* out = (float*)d_out;
  char* ws = (char*)d_ws;

  size_t o = 0;
  int* counts  = (int*)(ws + o);
  int* offsets = counts + 8;
  int* cursor  = counts + 16;
  o += 256;
  int*   route_e = (int*)(ws + o);   o += (size_t)TT * 2 * 4;
  float* route_w = (float*)(ws + o); o += (size_t)TT * 2 * 4;
  int*   tok_list = (int*)(ws + o);  o += (size_t)TT * 2 * 4;
  float* tok_w = (float*)(ws + o);   o += (size_t)TT * 2 * 4;
  unsigned short* xbf = (unsigned short*)(ws + o); o += (size_t)TT * DDIM * 2;
  size_t fixed = o;

  const size_t WSZ = (size_t)HDIM * DDIM;            // per-expert weight elems
  const size_t wbf_full = (size_t)NEXP * WSZ * 2;    // 235 MB each
  const size_t gfull = (size_t)TT * 2 * HDIM * 2;    // 235 MB

  hipMemsetAsync(counts, 0, 8 * sizeof(int), stream);
  hipMemsetAsync(out, 0, (size_t)TT * DDIM * sizeof(float), stream);
  cvt_bf16_kernel<<<4096, 256, 0, stream>>>(x, xbf, (long)TT * DDIM / 4);
  gate_kernel<<<TT, 256, 0, stream>>>(x, gate_w, route_e, route_w, counts);
  scan_kernel<<<1, 64, 0, stream>>>(counts, offsets, cursor);
  scatter_kernel<<<(TT + 255) / 256, 256, 0, stream>>>(route_e, route_w, cursor, tok_list, tok_w);

  if (ws_size >= fixed + 3 * wbf_full + gfull) {
    // Path A: full bf16 weight conversion, all experts in parallel
    unsigned short* w1b = (unsigned short*)(ws + fixed);
    unsigned short* w3b = w1b + NEXP * WSZ;
    unsigned short* w2t = w3b + NEXP * WSZ;
    unsigned short* gbuf = w2t + NEXP * WSZ;
    cvt_bf16_kernel<<<8192, 256, 0, stream>>>(w1, w1b, (long)(NEXP * WSZ / 4));
    cvt_bf16_kernel<<<8192, 256, 0, stream>>>(w3, w3b, (long)(NEXP * WSZ / 4));
    transpose_w2_kernel<<<dim3(HDIM / 64, DDIM / 64, NEXP), 256, 0, stream>>>(w2, w2t, -1);
    gemm1_kernel<<<NXB * NY1 * NEXP, 256, 0, stream>>>(
        xbf, w1b, w3b, tok_list, counts, offsets, gbuf, -1);
    gemm2_kernel<<<NXB * NY2 * NEXP, 256, 0, stream>>>(
        gbuf, w2t, tok_list, tok_w, counts, offsets, out, -1);
  } else {
    // Path B: sequential per-expert (fits in ~240 MB of ws)
    unsigned short* w1b = (unsigned short*)(ws + fixed);
    unsigned short* w3b = w1b + WSZ;
    unsigned short* w2t = w3b + WSZ;
    unsigned short* gbuf = w2t + WSZ;                // up to 8192 rows x HDIM
    for (int e = 0; e < NEXP; ++e) {
      cvt_bf16_kernel<<<4096, 256, 0, stream>>>(w1 + (size_t)e * WSZ, w1b, (long)(WSZ / 4));
      cvt_bf16_kernel<<<4096, 256, 0, stream>>>(w3 + (size_t)e * WSZ, w3b, (long)(WSZ / 4));
      transpose_w2_kernel<<<dim3(HDIM / 64, DDIM / 64, 1), 256, 0, stream>>>(w2, w2t, e);
      gemm1_kernel<<<NXB * NY1, 256, 0, stream>>>(
          xbf, w1b, w3b, tok_list, counts, offsets, gbuf, e);
      gemm2_kernel<<<NXB * NY2, 256, 0, stream>>>(
          gbuf, w2t, tok_list, tok_w, counts, offsets, out, e);
    }
  }
}